// Round 7
// baseline (175.870 us; speedup 1.0000x reference)
//
#include <hip/hip_runtime.h>
#include <hip/hip_bf16.h>
#include <math.h>

#define N 4096
#define D 256
#define SCALEF 10.0f
#define EPSF 1e-5f
#define MARGIN_INTRA 40.0f
#define MARGIN_INTER 6.0f
// reference excludes sorted_intra[0:4] = diagonal + top-3 non-diag, sorted_inter[0:6]
#define LI 3
#define LX 6
#define NJB 32              // j-blocks of 128
#define NIB 32              // i-blocks of 128
#define PPARTS (NJB * 2)    // partials per row: (j-block, wr)

typedef unsigned short ushort_t;
typedef __attribute__((ext_vector_type(8))) short short8;
typedef __attribute__((ext_vector_type(4))) float floatx4;

__device__ __forceinline__ float fast_sqrtf(float x) {
    return __builtin_amdgcn_sqrtf(x);
}

__device__ __forceinline__ ushort_t f2bf(float x) {
    __hip_bfloat16 h = __float2bfloat16(x);
    return *reinterpret_cast<ushort_t*>(&h);
}
__device__ __forceinline__ float bf2f(ushort_t u) {
    __hip_bfloat16 h = *reinterpret_cast<__hip_bfloat16*>(&u);
    return __bfloat162float(h);
}

template <int L>
__device__ __forceinline__ void bubble_insert(float (&t)[L], float v) {
#pragma unroll
    for (int q = 0; q < L; ++q) {
        float hi = fmaxf(t[q], v);
        v = fminf(t[q], v);
        t[q] = hi;
    }
}

// ---------------- Kernel 0: parallel counting sort of rows by camid ----------
// 1024 threads. Loss is row-permutation invariant, so the within-camera order
// is arbitrary -> wave-level atomic range reservation, no stability needed.
__global__ __launch_bounds__(1024) void perm_kernel(const int* __restrict__ camid,
                                                    int* __restrict__ perm,
                                                    int* __restrict__ camid_s,
                                                    float* __restrict__ out) {
    __shared__ int hist[8];
    __shared__ int offs[8];
    int tid = threadIdx.x;
    int lane = tid & 63;
    if (tid < 8) hist[tid] = 0;
    if (tid == 0) out[0] = 0.0f;
    __syncthreads();
    int v[4];
#pragma unroll
    for (int c = 0; c < 4; ++c) v[c] = camid[c * 1024 + tid];
#pragma unroll
    for (int c = 0; c < 4; ++c) {
#pragma unroll 1
        for (int cam = 0; cam < 8; ++cam) {
            unsigned long long m = __ballot(v[c] == cam);
            if (lane == 0 && m) atomicAdd(&hist[cam], __popcll(m));
        }
    }
    __syncthreads();
    if (tid == 0) {
        int run = 0;
#pragma unroll
        for (int cam = 0; cam < 8; ++cam) { offs[cam] = run; run += hist[cam]; }
    }
    __syncthreads();
#pragma unroll
    for (int c = 0; c < 4; ++c) {
        int idx = c * 1024 + tid;
#pragma unroll 1
        for (int cam = 0; cam < 8; ++cam) {
            unsigned long long m = __ballot(v[c] == cam);
            if (m) {
                int leader = __builtin_ctzll(m);
                int base = 0;
                if (lane == leader) base = atomicAdd(&offs[cam], __popcll(m));
                base = __shfl(base, leader, 64);
                if (v[c] == cam) {
                    int pre = __popcll(m & ((1ull << lane) - 1ull));
                    perm[base + pre] = idx;
                    camid_s[base + pre] = cam;
                }
            }
        }
    }
}

// ---------------- Kernel 1: gather + sq + R + bf16 hi/lo split ----------------
__global__ __launch_bounds__(64) void prep_kernel(const float* __restrict__ F,
                                                  const int* __restrict__ perm,
                                                  ushort_t* __restrict__ Fhi,
                                                  ushort_t* __restrict__ Flo,
                                                  float* __restrict__ sq,
                                                  float* __restrict__ Rrow) {
    int row = blockIdx.x;
    int orig = perm[row];
    int lane = threadIdx.x;
    float4 v = ((const float4*)(F + (size_t)orig * D))[lane];
    ushort4 h, l;
    h.x = f2bf(v.x); l.x = f2bf(v.x - bf2f(h.x));
    h.y = f2bf(v.y); l.y = f2bf(v.y - bf2f(h.y));
    h.z = f2bf(v.z); l.z = f2bf(v.z - bf2f(h.z));
    h.w = f2bf(v.w); l.w = f2bf(v.w - bf2f(h.w));
    ((ushort4*)(Fhi + (size_t)row * D))[lane] = h;
    ((ushort4*)(Flo + (size_t)row * D))[lane] = l;
    float s = v.x * v.x + v.y * v.y + v.z * v.z + v.w * v.w;
#pragma unroll
    for (int off = 32; off > 0; off >>= 1) s += __shfl_down(s, off, 64);
    if (lane == 0) {
        sq[row] = s;
        Rrow[row] = -SCALEF * sqrtf(2.0f * s);  // per-row exp reference shift
    }
}

// ---------------- Kernel 2: fused GEMM + online masked-topk-LSE ----------------
// Block: 128 i x 128 j (camera-sorted space), 2x2 waves of 64x64.
// NO LDS, NO barriers: the 16x16x32 A/B fragment layout (m=lane&15,
// k=quad*8+j, 8 contiguous k) is exactly a row-major 16B segment, so
// fragments load DIRECTLY from global (L2-resident, 4 MB total).
// Gram tile TRANSPOSED: A <- j-features, B <- i-features, so each lane's
// accumulator holds 4 rows (ni) x 16 j.
__global__ __launch_bounds__(256, 3) void fused_kernel(
    const ushort_t* __restrict__ Fhi, const ushort_t* __restrict__ Flo,
    const float* __restrict__ sq, const float* __restrict__ Rrow,
    const int* __restrict__ camid_s,
    float4* __restrict__ partA, float4* __restrict__ partB, float4* __restrict__ partC) {
    int tid = threadIdx.x;
    int wave = tid >> 6, lane = tid & 63;
    int wr = wave >> 1, wc = wave & 1;   // wr: j-half (64), wc: i-half (64)
    int lane15 = lane & 15, quad = lane >> 4;
    int cid = blockIdx.x, sid = blockIdx.y;
    int i0 = sid * 128, j0 = cid * 128;

    // block-uniform camera-range disjointness (camid_s is sorted)
    int ci_lo = camid_s[i0], ci_hi = camid_s[i0 + 127];
    int cj_lo = camid_s[j0], cj_hi = camid_s[j0 + 127];
    bool disjoint = (ci_hi < cj_lo) || (cj_hi < ci_lo);

    float si[4], Ri4[4];
    int ci4[4], ig[4];
#pragma unroll
    for (int ni = 0; ni < 4; ++ni) {
        int i = i0 + wc * 64 + ni * 16 + lane15;
        ig[ni] = i;
        si[ni] = sq[i];
        Ri4[ni] = Rrow[i];
        ci4[ni] = camid_s[i];
    }

    float tI[4][LI], tX[4][LX], sIa[4], sXa[4];
#pragma unroll
    for (int ni = 0; ni < 4; ++ni) {
#pragma unroll
        for (int q = 0; q < LI; ++q) tI[ni][q] = -INFINITY;
#pragma unroll
        for (int q = 0; q < LX; ++q) tX[ni][q] = -INFINITY;
        sIa[ni] = 0.0f; sXa[ni] = 0.0f;
    }

    // direct-global fragment base pointers (16B-aligned)
    const size_t aoff = (size_t)(j0 + wr * 64 + lane15) * D + quad * 8;
    const size_t boff = (size_t)(i0 + wc * 64 + lane15) * D + quad * 8;
    const ushort_t* pAh = Fhi + aoff;
    const ushort_t* pAl = Flo + aoff;
    const ushort_t* pBh = Fhi + boff;
    const ushort_t* pBl = Flo + boff;

    floatx4 acc[4][4] = {};

#pragma unroll 2
    for (int kt = 0; kt < 8; ++kt) {
        int ko = kt * 32;
        short8 ahi[4], alo[4], bhi[4], blo[4];
#pragma unroll
        for (int mi = 0; mi < 4; ++mi) {
            ahi[mi] = *(const short8*)(pAh + mi * 16 * D + ko);
            alo[mi] = *(const short8*)(pAl + mi * 16 * D + ko);
        }
#pragma unroll
        for (int ni = 0; ni < 4; ++ni) {
            bhi[ni] = *(const short8*)(pBh + ni * 16 * D + ko);
            blo[ni] = *(const short8*)(pBl + ni * 16 * D + ko);
        }
#pragma unroll
        for (int mi = 0; mi < 4; ++mi)
#pragma unroll
            for (int ni = 0; ni < 4; ++ni) {
                acc[mi][ni] = __builtin_amdgcn_mfma_f32_16x16x32_bf16(ahi[mi], bhi[ni], acc[mi][ni], 0, 0, 0);
                acc[mi][ni] = __builtin_amdgcn_mfma_f32_16x16x32_bf16(ahi[mi], blo[ni], acc[mi][ni], 0, 0, 0);
                acc[mi][ni] = __builtin_amdgcn_mfma_f32_16x16x32_bf16(alo[mi], bhi[ni], acc[mi][ni], 0, 0, 0);
            }
    }

    // epilogue: acc[mi][ni][r] <-> (j = j0 + wr*64 + mi*16 + quad*4 + r, i = ig[ni])
    if (disjoint) {
        // pure inter: no intra path, no camid compare, no diagonal possible
#pragma unroll
        for (int mi = 0; mi < 4; ++mi) {
            int jg0 = j0 + wr * 64 + mi * 16 + quad * 4;
            float4 sj4 = *(const float4*)(sq + jg0);
            const float* sjp = (const float*)&sj4;
#pragma unroll
            for (int ni = 0; ni < 4; ++ni) {
                float sb = si[ni] + EPSF;
#pragma unroll
                for (int r = 0; r < 4; ++r) {
                    float d2 = fmaxf(fmaf(-2.0f, acc[mi][ni][r], sb + sjp[r]), 1e-12f);
                    float x = -SCALEF * fast_sqrtf(d2);
                    sXa[ni] += __expf(x - Ri4[ni]);
                    bubble_insert<LX>(tX[ni], x);
                }
            }
        }
    } else {
#pragma unroll
        for (int mi = 0; mi < 4; ++mi) {
            int jg0 = j0 + wr * 64 + mi * 16 + quad * 4;
            float4 sj4 = *(const float4*)(sq + jg0);
            int4 cj4 = *(const int4*)(camid_s + jg0);
            const float* sjp = (const float*)&sj4;
            const int* cjp = (const int*)&cj4;
#pragma unroll
            for (int ni = 0; ni < 4; ++ni) {
                int dd = jg0 - ig[ni];  // diagonal at r == -dd
                float sb = si[ni] + EPSF;
#pragma unroll
                for (int r = 0; r < 4; ++r) {
                    float d2 = fmaxf(fmaf(-2.0f, acc[mi][ni][r], sb + sjp[r]), 1e-12f);
                    float x = -SCALEF * fast_sqrtf(d2);
                    float e = __expf(x - Ri4[ni]);
                    bool ii = (cjp[r] == ci4[ni]);
                    bool dg = ((dd + r) == 0);
                    bool okI = ii && !dg;
                    sIa[ni] += okI ? e : 0.0f;
                    sXa[ni] += ii ? 0.0f : e;
                    bubble_insert<LI>(tI[ni], okI ? x : -INFINITY);
                    bubble_insert<LX>(tX[ni], ii ? -INFINITY : x);
                }
            }
        }
    }

    // merge across the 4 quads sharing each row (butterfly, offsets 16 & 32).
    // Snapshot ALL partner values BEFORE mutating own lists (lockstep hazard).
#pragma unroll
    for (int off = 16; off <= 32; off <<= 1) {
#pragma unroll
        for (int ni = 0; ni < 4; ++ni) {
            sIa[ni] += __shfl_xor(sIa[ni], off, 64);
            sXa[ni] += __shfl_xor(sXa[ni], off, 64);
            float oI[LI], oX[LX];
#pragma unroll
            for (int q = 0; q < LI; ++q) oI[q] = __shfl_xor(tI[ni][q], off, 64);
#pragma unroll
            for (int q = 0; q < LX; ++q) oX[q] = __shfl_xor(tX[ni][q], off, 64);
#pragma unroll
            for (int q = 0; q < LI; ++q) bubble_insert<LI>(tI[ni], oI[q]);
#pragma unroll
            for (int q = 0; q < LX; ++q) bubble_insert<LX>(tX[ni], oX[q]);
        }
    }

    if (quad == 0) {
        int p = cid * 2 + wr;
#pragma unroll
        for (int ni = 0; ni < 4; ++ni) {
            size_t idx = (size_t)p * N + ig[ni];
            partA[idx] = make_float4(tI[ni][0], tI[ni][1], tI[ni][2], sIa[ni]);
            partB[idx] = make_float4(tX[ni][0], tX[ni][1], tX[ni][2], tX[ni][3]);
            partC[idx] = make_float4(tX[ni][4], tX[ni][5], sXa[ni], 0.0f);
        }
    }
}

// ---------------- Kernel 3: merge partials -> loss (atomic accumulate) --------
__global__ __launch_bounds__(256) void merge_kernel(const float4* __restrict__ partA,
                                                    const float4* __restrict__ partB,
                                                    const float4* __restrict__ partC,
                                                    const float* __restrict__ Rrow,
                                                    float* __restrict__ out) {
    __shared__ float sbuf[256];
    int tid = threadIdx.x;
    int row = blockIdx.x * 256 + tid;
    float mI[LI] = {-INFINITY, -INFINITY, -INFINITY};
    float mX[LX] = {-INFINITY, -INFINITY, -INFINITY, -INFINITY, -INFINITY, -INFINITY};
    float SI = 0.0f, SX = 0.0f;
#pragma unroll 1
    for (int p = 0; p < PPARTS; ++p) {
        size_t idx = (size_t)p * N + row;
        float4 a = partA[idx];
        float4 b = partB[idx];
        float4 c = partC[idx];
        bubble_insert<LI>(mI, a.x); bubble_insert<LI>(mI, a.y); bubble_insert<LI>(mI, a.z);
        SI += a.w;
        bubble_insert<LX>(mX, b.x); bubble_insert<LX>(mX, b.y);
        bubble_insert<LX>(mX, b.z); bubble_insert<LX>(mX, b.w);
        bubble_insert<LX>(mX, c.x); bubble_insert<LX>(mX, c.y);
        SX += c.z;
    }
    float R = Rrow[row];
    // intra: exclude diag (by construction) + top-3 values
    float subI = __expf(mI[0] - R) + __expf(mI[1] - R) + __expf(mI[2] - R);
    float restI = fmaxf(SI - subI, 1e-37f);
    float yI = R + logf(restI);
    float hI = fmaxf(yI + SCALEF * sqrtf(EPSF) + MARGIN_INTRA, 0.0f);  // -x0 = +10*sqrt(eps)
    // inter: exclude top-6 values
    float subX = __expf(mX[0] - R) + __expf(mX[1] - R) + __expf(mX[2] - R) +
                 __expf(mX[3] - R) + __expf(mX[4] - R) + __expf(mX[5] - R);
    float restX = fmaxf(SX - subX, 1e-37f);
    float yX = R + logf(restX);
    float hX = fmaxf(-mX[0] + yX + MARGIN_INTER, 0.0f);
    sbuf[tid] = hI + 0.5f * hX;
    __syncthreads();
    for (int stride = 128; stride > 0; stride >>= 1) {
        if (tid < stride) sbuf[tid] += sbuf[tid + stride];
        __syncthreads();
    }
    if (tid == 0) atomicAdd(out, sbuf[0] * (1.0f / (float)N));
}

extern "C" void kernel_launch(void* const* d_in, const int* in_sizes, int n_in,
                              void* d_out, int out_size, void* d_ws, size_t ws_size,
                              hipStream_t stream) {
    const float* F = (const float*)d_in[0];
    const int* camid = (const int*)d_in[1];
    float* out = (float*)d_out;
    char* ws = (char*)d_ws;

    ushort_t* Fhi = (ushort_t*)ws;                               // 2 MB
    ushort_t* Flo = Fhi + (size_t)N * D;                         // 2 MB
    float* sq = (float*)(ws + 2 * (size_t)N * D * 2);            // 16 KB
    float* Rrow = sq + N;                                        // 16 KB
    int* perm = (int*)(Rrow + N);                                // 16 KB
    int* camid_s = perm + N;                                     // 16 KB
    float4* partA = (float4*)(ws + 2 * (size_t)N * D * 2 + 4 * N * 4);  // 4 MB each
    float4* partB = partA + (size_t)PPARTS * N;
    float4* partC = partB + (size_t)PPARTS * N;

    perm_kernel<<<1, 1024, 0, stream>>>(camid, perm, camid_s, out);
    prep_kernel<<<N, 64, 0, stream>>>(F, perm, Fhi, Flo, sq, Rrow);
    fused_kernel<<<dim3(NJB, NIB), 256, 0, stream>>>(Fhi, Flo, sq, Rrow, camid_s,
                                                     partA, partB, partC);
    merge_kernel<<<N / 256, 256, 0, stream>>>(partA, partB, partC, Rrow, out);
}

// Round 8
// 140.306 us; speedup vs baseline: 1.2535x; 1.2535x over previous
//
#include <hip/hip_runtime.h>
#include <hip/hip_bf16.h>
#include <math.h>

#define N 4096
#define D 256
#define SCALEF 10.0f
#define EPSF 1e-5f
#define MARGIN_INTRA 40.0f
#define MARGIN_INTER 6.0f
// reference excludes sorted_intra[0:4] = diagonal + top-3 non-diag, sorted_inter[0:6]
#define LI 3
#define LX 6
#define NJB 32              // j-blocks of 128
#define NIB 32              // i-blocks of 128
#define PPARTS (NJB * 2)    // partials per row: (j-block, wr) == 64 == wave size

typedef unsigned short ushort_t;
typedef __attribute__((ext_vector_type(8))) short short8;
typedef __attribute__((ext_vector_type(4))) float floatx4;

__device__ __forceinline__ float fast_sqrtf(float x) {
    return __builtin_amdgcn_sqrtf(x);
}

__device__ __forceinline__ ushort_t f2bf(float x) {
    __hip_bfloat16 h = __float2bfloat16(x);
    return *reinterpret_cast<ushort_t*>(&h);
}
__device__ __forceinline__ float bf2f(ushort_t u) {
    __hip_bfloat16 h = *reinterpret_cast<__hip_bfloat16*>(&u);
    return __bfloat162float(h);
}

// async global->LDS DMA, 16 B per lane. LDS dst = wave-uniform base + lane*16.
typedef __attribute__((address_space(1))) void gvoid;
typedef __attribute__((address_space(3))) void svoid;
__device__ __forceinline__ void gld16(const ushort_t* g, ushort_t* l) {
    __builtin_amdgcn_global_load_lds((gvoid*)g, (svoid*)l, 16, 0, 0);
}

template <int L>
__device__ __forceinline__ void bubble_insert(float (&t)[L], float v) {
#pragma unroll
    for (int q = 0; q < L; ++q) {
        float hi = fmaxf(t[q], v);
        v = fminf(t[q], v);
        t[q] = hi;
    }
}

// ---------------- Kernel 0: parallel counting sort of rows by camid ----------
// Loss is row-permutation invariant -> atomic range reservation, no stability.
__global__ __launch_bounds__(1024) void perm_kernel(const int* __restrict__ camid,
                                                    int* __restrict__ perm,
                                                    int* __restrict__ camid_s,
                                                    float* __restrict__ out) {
    __shared__ int hist[8];
    __shared__ int offs[8];
    int tid = threadIdx.x;
    int lane = tid & 63;
    if (tid < 8) hist[tid] = 0;
    if (tid == 0) out[0] = 0.0f;
    __syncthreads();
    int v[4];
#pragma unroll
    for (int c = 0; c < 4; ++c) v[c] = camid[c * 1024 + tid];
#pragma unroll
    for (int c = 0; c < 4; ++c) {
#pragma unroll 1
        for (int cam = 0; cam < 8; ++cam) {
            unsigned long long m = __ballot(v[c] == cam);
            if (lane == 0 && m) atomicAdd(&hist[cam], __popcll(m));
        }
    }
    __syncthreads();
    if (tid == 0) {
        int run = 0;
#pragma unroll
        for (int cam = 0; cam < 8; ++cam) { offs[cam] = run; run += hist[cam]; }
    }
    __syncthreads();
#pragma unroll
    for (int c = 0; c < 4; ++c) {
        int idx = c * 1024 + tid;
#pragma unroll 1
        for (int cam = 0; cam < 8; ++cam) {
            unsigned long long m = __ballot(v[c] == cam);
            if (m) {
                int leader = __builtin_ctzll(m);
                int base = 0;
                if (lane == leader) base = atomicAdd(&offs[cam], __popcll(m));
                base = __shfl(base, leader, 64);
                if (v[c] == cam) {
                    int pre = __popcll(m & ((1ull << lane) - 1ull));
                    perm[base + pre] = idx;
                    camid_s[base + pre] = cam;
                }
            }
        }
    }
}

// ---------------- Kernel 1: gather + sq + R + bf16 hi/lo split ----------------
__global__ __launch_bounds__(256) void prep_kernel(const float* __restrict__ F,
                                                   const int* __restrict__ perm,
                                                   ushort_t* __restrict__ Fhi,
                                                   ushort_t* __restrict__ Flo,
                                                   float* __restrict__ sq,
                                                   float* __restrict__ Rrow) {
    int wv = threadIdx.x >> 6, lane = threadIdx.x & 63;
    int row = blockIdx.x * 4 + wv;
    int orig = perm[row];
    float4 v = ((const float4*)(F + (size_t)orig * D))[lane];
    ushort4 h, l;
    h.x = f2bf(v.x); l.x = f2bf(v.x - bf2f(h.x));
    h.y = f2bf(v.y); l.y = f2bf(v.y - bf2f(h.y));
    h.z = f2bf(v.z); l.z = f2bf(v.z - bf2f(h.z));
    h.w = f2bf(v.w); l.w = f2bf(v.w - bf2f(h.w));
    ((ushort4*)(Fhi + (size_t)row * D))[lane] = h;
    ((ushort4*)(Flo + (size_t)row * D))[lane] = l;
    float s = v.x * v.x + v.y * v.y + v.z * v.z + v.w * v.w;
#pragma unroll
    for (int off = 32; off > 0; off >>= 1) s += __shfl_down(s, off, 64);
    if (lane == 0) {
        sq[row] = s;
        Rrow[row] = -SCALEF * sqrtf(2.0f * s);  // per-row exp reference shift
    }
}

// ---------------- Kernel 2: fused GEMM + online masked-topk-LSE ----------------
// Block: 128 i x 128 j (camera-sorted space), 2x2 waves of 64x64.
// Staging via global_load_lds(16B) into FRAGMENT-ORDERED LDS: 16B piece of
// (row r, k-octet o) lives at unit (r>>4)*64 + o*16 + (r&15); a fragment read
// is then per-lane-contiguous 1 KB (ds_read_b128, conflict-free, no padding).
// Gram tile TRANSPOSED: A <- j-features, B <- i-features; each lane's
// accumulator holds 4 rows (ni) x 16 j.
__global__ __launch_bounds__(256, 3) void fused_kernel(
    const ushort_t* __restrict__ Fhi, const ushort_t* __restrict__ Flo,
    const float* __restrict__ sq, const float* __restrict__ Rrow,
    const int* __restrict__ camid_s,
    float4* __restrict__ partA, float4* __restrict__ partB, float4* __restrict__ partC) {
    __shared__ ushort_t lds[4][4096];  // Ahi, Alo, Bhi, Blo: 8 KB each = 32768 B
    int tid = threadIdx.x;
    int wave = tid >> 6, lane = tid & 63;
    int wr = wave >> 1, wc = wave & 1;   // wr: j-half (64), wc: i-half (64)
    int lane15 = lane & 15, quad = lane >> 4;
    int cid = blockIdx.x, sid = blockIdx.y;
    int i0 = sid * 128, j0 = cid * 128;

    // block-uniform camera-range disjointness (camid_s is sorted)
    int ci_lo = camid_s[i0], ci_hi = camid_s[i0 + 127];
    int cj_lo = camid_s[j0], cj_hi = camid_s[j0 + 127];
    bool disjoint = (ci_hi < cj_lo) || (cj_hi < ci_lo);

    float si[4], Ri4[4];
    int ci4[4], ig[4];
#pragma unroll
    for (int ni = 0; ni < 4; ++ni) {
        int i = i0 + wc * 64 + ni * 16 + lane15;
        ig[ni] = i;
        si[ni] = sq[i];
        Ri4[ni] = Rrow[i];
        ci4[ni] = camid_s[i];
    }

    float tI[4][LI], tX[4][LX], sIa[4], sXa[4];
#pragma unroll
    for (int ni = 0; ni < 4; ++ni) {
#pragma unroll
        for (int q = 0; q < LI; ++q) tI[ni][q] = -INFINITY;
#pragma unroll
        for (int q = 0; q < LX; ++q) tX[ni][q] = -INFINITY;
        sIa[ni] = 0.0f; sXa[ni] = 0.0f;
    }

    // DMA source offsets: unit u = wave*128 + t*64 + lane (t=0,1)
    //   row_local(u) = (u>>6)*16 + (u&15), k-octet(u) = (u>>4)&3
    int u0 = wave * 128 + lane;
    int u1 = u0 + 64;
    int rl0 = ((u0 >> 6) << 4) | (u0 & 15), oc0 = (u0 >> 4) & 3;
    int rl1 = ((u1 >> 6) << 4) | (u1 & 15), oc1 = (u1 >> 4) & 3;
    size_t offA0 = (size_t)(j0 + rl0) * D + oc0 * 8;
    size_t offA1 = (size_t)(j0 + rl1) * D + oc1 * 8;
    size_t offB0 = (size_t)(i0 + rl0) * D + oc0 * 8;
    size_t offB1 = (size_t)(i0 + rl1) * D + oc1 * 8;
    // wave-uniform LDS dst (ushort units): wave*1024 + t*512
    ushort_t* d0 = &lds[0][wave * 1024];

    floatx4 acc[4][4] = {};

#pragma unroll 1
    for (int kt = 0; kt < 8; ++kt) {
        int ko = kt * 32;
        __syncthreads();  // prior iteration's fragment reads complete
        gld16(Fhi + offA0 + ko, d0 + 0 * 4096);
        gld16(Fhi + offA1 + ko, d0 + 0 * 4096 + 512);
        gld16(Flo + offA0 + ko, d0 + 1 * 4096);
        gld16(Flo + offA1 + ko, d0 + 1 * 4096 + 512);
        gld16(Fhi + offB0 + ko, d0 + 2 * 4096);
        gld16(Fhi + offB1 + ko, d0 + 2 * 4096 + 512);
        gld16(Flo + offB0 + ko, d0 + 3 * 4096);
        gld16(Flo + offB1 + ko, d0 + 3 * 4096 + 512);
        __syncthreads();  // vmcnt(0) drain => DMA landed for all waves

        short8 ahi[4], alo[4], bhi[4], blo[4];
        int fo = lane * 8;
#pragma unroll
        for (int mi = 0; mi < 4; ++mi) {
            int b = (wr * 4 + mi) * 512 + fo;
            ahi[mi] = *(const short8*)&lds[0][b];
            alo[mi] = *(const short8*)&lds[1][b];
        }
#pragma unroll
        for (int ni = 0; ni < 4; ++ni) {
            int b = (wc * 4 + ni) * 512 + fo;
            bhi[ni] = *(const short8*)&lds[2][b];
            blo[ni] = *(const short8*)&lds[3][b];
        }
#pragma unroll
        for (int mi = 0; mi < 4; ++mi)
#pragma unroll
            for (int ni = 0; ni < 4; ++ni) {
                acc[mi][ni] = __builtin_amdgcn_mfma_f32_16x16x32_bf16(ahi[mi], bhi[ni], acc[mi][ni], 0, 0, 0);
                acc[mi][ni] = __builtin_amdgcn_mfma_f32_16x16x32_bf16(ahi[mi], blo[ni], acc[mi][ni], 0, 0, 0);
                acc[mi][ni] = __builtin_amdgcn_mfma_f32_16x16x32_bf16(alo[mi], bhi[ni], acc[mi][ni], 0, 0, 0);
            }
    }

    // epilogue: acc[mi][ni][r] <-> (j = j0 + wr*64 + mi*16 + quad*4 + r, i = ig[ni])
    if (disjoint) {
        // pure inter: no intra path, no camid compare, no diagonal possible
#pragma unroll
        for (int mi = 0; mi < 4; ++mi) {
            int jg0 = j0 + wr * 64 + mi * 16 + quad * 4;
            float4 sj4 = *(const float4*)(sq + jg0);
            const float* sjp = (const float*)&sj4;
#pragma unroll
            for (int ni = 0; ni < 4; ++ni) {
                float sb = si[ni] + EPSF;
#pragma unroll
                for (int r = 0; r < 4; ++r) {
                    float d2 = fmaxf(fmaf(-2.0f, acc[mi][ni][r], sb + sjp[r]), 1e-12f);
                    float x = -SCALEF * fast_sqrtf(d2);
                    sXa[ni] += __expf(x - Ri4[ni]);
                    bubble_insert<LX>(tX[ni], x);
                }
            }
        }
    } else {
#pragma unroll
        for (int mi = 0; mi < 4; ++mi) {
            int jg0 = j0 + wr * 64 + mi * 16 + quad * 4;
            float4 sj4 = *(const float4*)(sq + jg0);
            int4 cj4 = *(const int4*)(camid_s + jg0);
            const float* sjp = (const float*)&sj4;
            const int* cjp = (const int*)&cj4;
#pragma unroll
            for (int ni = 0; ni < 4; ++ni) {
                int dd = jg0 - ig[ni];  // diagonal at r == -dd
                float sb = si[ni] + EPSF;
#pragma unroll
                for (int r = 0; r < 4; ++r) {
                    float d2 = fmaxf(fmaf(-2.0f, acc[mi][ni][r], sb + sjp[r]), 1e-12f);
                    float x = -SCALEF * fast_sqrtf(d2);
                    float e = __expf(x - Ri4[ni]);
                    bool ii = (cjp[r] == ci4[ni]);
                    bool dg = ((dd + r) == 0);
                    bool okI = ii && !dg;
                    sIa[ni] += okI ? e : 0.0f;
                    sXa[ni] += ii ? 0.0f : e;
                    bubble_insert<LI>(tI[ni], okI ? x : -INFINITY);
                    bubble_insert<LX>(tX[ni], ii ? -INFINITY : x);
                }
            }
        }
    }

    // merge across the 4 quads sharing each row (butterfly, offsets 16 & 32).
    // Snapshot ALL partner values BEFORE mutating own lists (lockstep hazard).
#pragma unroll
    for (int off = 16; off <= 32; off <<= 1) {
#pragma unroll
        for (int ni = 0; ni < 4; ++ni) {
            sIa[ni] += __shfl_xor(sIa[ni], off, 64);
            sXa[ni] += __shfl_xor(sXa[ni], off, 64);
            float oI[LI], oX[LX];
#pragma unroll
            for (int q = 0; q < LI; ++q) oI[q] = __shfl_xor(tI[ni][q], off, 64);
#pragma unroll
            for (int q = 0; q < LX; ++q) oX[q] = __shfl_xor(tX[ni][q], off, 64);
#pragma unroll
            for (int q = 0; q < LI; ++q) bubble_insert<LI>(tI[ni], oI[q]);
#pragma unroll
            for (int q = 0; q < LX; ++q) bubble_insert<LX>(tX[ni], oX[q]);
        }
    }

    if (quad == 0) {
        int p = cid * 2 + wr;
#pragma unroll
        for (int ni = 0; ni < 4; ++ni) {
            size_t idx = (size_t)p * N + ig[ni];
            partA[idx] = make_float4(tI[ni][0], tI[ni][1], tI[ni][2], sIa[ni]);
            partB[idx] = make_float4(tX[ni][0], tX[ni][1], tX[ni][2], tX[ni][3]);
            partC[idx] = make_float4(tX[ni][4], tX[ni][5], sXa[ni], 0.0f);
        }
    }
}

// ---------------- Kernel 3: wave-per-row merge of 64 partials -> loss ---------
__global__ __launch_bounds__(256) void merge_kernel(const float4* __restrict__ partA,
                                                    const float4* __restrict__ partB,
                                                    const float4* __restrict__ partC,
                                                    const float* __restrict__ Rrow,
                                                    float* __restrict__ out) {
    __shared__ float sbuf[4];
    int wv = threadIdx.x >> 6, lane = threadIdx.x & 63;
    int row = blockIdx.x * 4 + wv;
    size_t idx = (size_t)lane * N + row;  // lane == partial index (PPARTS==64)
    float4 a = partA[idx];
    float4 b = partB[idx];
    float4 c = partC[idx];
    float mI[LI] = {a.x, a.y, a.z};
    float mX[LX] = {b.x, b.y, b.z, b.w, c.x, c.y};
    float SI = a.w, SX = c.z;
#pragma unroll
    for (int off = 32; off >= 1; off >>= 1) {
        SI += __shfl_xor(SI, off, 64);
        SX += __shfl_xor(SX, off, 64);
        float oI[LI], oX[LX];
#pragma unroll
        for (int q = 0; q < LI; ++q) oI[q] = __shfl_xor(mI[q], off, 64);
#pragma unroll
        for (int q = 0; q < LX; ++q) oX[q] = __shfl_xor(mX[q], off, 64);
#pragma unroll
        for (int q = 0; q < LI; ++q) bubble_insert<LI>(mI, oI[q]);
#pragma unroll
        for (int q = 0; q < LX; ++q) bubble_insert<LX>(mX, oX[q]);
    }
    if (lane == 0) {
        float R = Rrow[row];
        // intra: exclude diag (by construction) + top-3 values
        float subI = __expf(mI[0] - R) + __expf(mI[1] - R) + __expf(mI[2] - R);
        float restI = fmaxf(SI - subI, 1e-37f);
        float yI = R + logf(restI);
        float hI = fmaxf(yI + SCALEF * sqrtf(EPSF) + MARGIN_INTRA, 0.0f);
        // inter: exclude top-6 values
        float subX = __expf(mX[0] - R) + __expf(mX[1] - R) + __expf(mX[2] - R) +
                     __expf(mX[3] - R) + __expf(mX[4] - R) + __expf(mX[5] - R);
        float restX = fmaxf(SX - subX, 1e-37f);
        float yX = R + logf(restX);
        float hX = fmaxf(-mX[0] + yX + MARGIN_INTER, 0.0f);
        sbuf[wv] = hI + 0.5f * hX;
    }
    __syncthreads();
    if (threadIdx.x == 0) {
        float s = sbuf[0] + sbuf[1] + sbuf[2] + sbuf[3];
        atomicAdd(out, s * (1.0f / (float)N));
    }
}

extern "C" void kernel_launch(void* const* d_in, const int* in_sizes, int n_in,
                              void* d_out, int out_size, void* d_ws, size_t ws_size,
                              hipStream_t stream) {
    const float* F = (const float*)d_in[0];
    const int* camid = (const int*)d_in[1];
    float* out = (float*)d_out;
    char* ws = (char*)d_ws;

    ushort_t* Fhi = (ushort_t*)ws;                               // 2 MB
    ushort_t* Flo = Fhi + (size_t)N * D;                         // 2 MB
    float* sq = (float*)(ws + 2 * (size_t)N * D * 2);            // 16 KB
    float* Rrow = sq + N;                                        // 16 KB
    int* perm = (int*)(Rrow + N);                                // 16 KB
    int* camid_s = perm + N;                                     // 16 KB
    float4* partA = (float4*)(ws + 2 * (size_t)N * D * 2 + 4 * N * 4);  // 4 MB each
    float4* partB = partA + (size_t)PPARTS * N;
    float4* partC = partB + (size_t)PPARTS * N;

    perm_kernel<<<1, 1024, 0, stream>>>(camid, perm, camid_s, out);
    prep_kernel<<<N / 4, 256, 0, stream>>>(F, perm, Fhi, Flo, sq, Rrow);
    fused_kernel<<<dim3(NJB, NIB), 256, 0, stream>>>(Fhi, Flo, sq, Rrow, camid_s,
                                                     partA, partB, partC);
    merge_kernel<<<N / 4, 256, 0, stream>>>(partA, partB, partC, Rrow, out);
}